// Round 5
// baseline (975.945 us; speedup 1.0000x reference)
//
#include <hip/hip_runtime.h>

constexpr int F_IN = 512;
constexpr int HID  = 64;
constexpr int OUTD = 32;
constexpr int NH   = 4;
constexpr int HO1  = NH * HID;   // 256
constexpr int HO2  = NH * OUTD;  // 128

// ---------------- CSR build ----------------

__global__ void zero_i32(int* p, int n) {
  int i = blockIdx.x * blockDim.x + threadIdx.x;
  if (i < n) p[i] = 0;
}

__global__ void count_kernel(const int* __restrict__ src, int* __restrict__ cnt, int E) {
  int i = blockIdx.x * blockDim.x + threadIdx.x;
  if (i < E) atomicAdd(&cnt[src[i]], 1);
}

// single-block exclusive scan over n counts -> row[0..n], cursor copy
__global__ void scan_kernel(const int* __restrict__ cnt, int* __restrict__ row,
                            int* __restrict__ cursor, int n) {
  __shared__ int wsum[16];
  __shared__ int carry_s;
  int t = threadIdx.x;
  if (t == 0) carry_s = 0;
  __syncthreads();
  for (int base = 0; base < n; base += 1024) {
    int i = base + t;
    int c = (i < n) ? cnt[i] : 0;
    int v = c;
    #pragma unroll
    for (int off = 1; off < 64; off <<= 1) {
      int u = __shfl_up(v, off);
      if ((t & 63) >= off) v += u;
    }
    if ((t & 63) == 63) wsum[t >> 6] = v;
    __syncthreads();
    if (t < 16) {
      int w = wsum[t];
      #pragma unroll
      for (int off = 1; off < 16; off <<= 1) {
        int u = __shfl_up(w, off);
        if (t >= off) w += u;
      }
      wsum[t] = w;
    }
    __syncthreads();
    int waveoff = (t >> 6) ? wsum[(t >> 6) - 1] : 0;
    int carry = carry_s;
    int incl = v + waveoff + carry;
    if (i < n) { row[i] = incl - c; cursor[i] = incl - c; }
    __syncthreads();
    if (t == 1023) carry_s = incl;
    __syncthreads();
  }
  if (t == 0) row[n] = carry_s;
}

__global__ void scatter_kernel(const int* __restrict__ src, const int* __restrict__ dst,
                               int* __restrict__ cursor, int* __restrict__ dsts, int E) {
  int i = blockIdx.x * blockDim.x + threadIdx.x;
  if (i < E) {
    int s = src[i];
    int p = atomicAdd(&cursor[s], 1);
    dsts[p] = dst[i];
  }
}

// ---------------- weight rearrange (H,K,O) -> (K, H*O) ----------------

template<int K, int O>
__global__ void rearrange_W(const float* __restrict__ W, float* __restrict__ Br, int total) {
  int i = blockIdx.x * blockDim.x + threadIdx.x;
  if (i >= total) return;
  int o = i % O;
  int f = (i / O) % K;
  int h = i / (O * K);
  Br[f * (NH * O) + h * O + o] = W[i];
}

// ---------------- f32 SGEMM: C(MxNC) = A(MxK) @ B(KxNC) ----------------
// BM=BN=128, BK=16, 256 threads, 8x8 per thread.

template<int K, int NC>
__global__ __launch_bounds__(256) void gemm_f32(const float* __restrict__ A,
                                                const float* __restrict__ B,
                                                float* __restrict__ C, int M) {
  constexpr int BM = 128, BN = 128, BK = 16;
  __shared__ float As[BK][BM + 4];   // row stride 132 floats = 528B (16B-mult)
  __shared__ float Bs[BK][BN];
  int t  = threadIdx.x;
  int tx = t % 16, ty = t / 16;
  int row0 = blockIdx.x * BM;
  int col0 = blockIdx.y * BN;

  float acc[8][8] = {};

  for (int k0 = 0; k0 < K; k0 += BK) {
    #pragma unroll
    for (int i = 0; i < 2; ++i) {
      // A tile: 128 rows x 16 k, float4 along k
      int r  = t / 4 + 64 * i;
      int kq = t % 4;
      float4 av = make_float4(0.f, 0.f, 0.f, 0.f);
      int grow = row0 + r;
      if (grow < M) av = *reinterpret_cast<const float4*>(&A[(size_t)grow * K + k0 + kq * 4]);
      As[kq * 4 + 0][r] = av.x;
      As[kq * 4 + 1][r] = av.y;
      As[kq * 4 + 2][r] = av.z;
      As[kq * 4 + 3][r] = av.w;
      // B tile: 16 k-rows x 128 cols
      int kr = t / 32 + 8 * i;
      int cq = t % 32;
      float4 bv = *reinterpret_cast<const float4*>(&B[(size_t)(k0 + kr) * NC + col0 + cq * 4]);
      *reinterpret_cast<float4*>(&Bs[kr][cq * 4]) = bv;
    }
    __syncthreads();
    #pragma unroll
    for (int kk = 0; kk < BK; ++kk) {
      float4 a0 = *reinterpret_cast<const float4*>(&As[kk][ty * 8]);
      float4 a1 = *reinterpret_cast<const float4*>(&As[kk][ty * 8 + 4]);
      float4 b0 = *reinterpret_cast<const float4*>(&Bs[kk][tx * 8]);
      float4 b1 = *reinterpret_cast<const float4*>(&Bs[kk][tx * 8 + 4]);
      float a[8] = {a0.x, a0.y, a0.z, a0.w, a1.x, a1.y, a1.z, a1.w};
      float b[8] = {b0.x, b0.y, b0.z, b0.w, b1.x, b1.y, b1.z, b1.w};
      #pragma unroll
      for (int i = 0; i < 8; ++i)
        #pragma unroll
        for (int j = 0; j < 8; ++j)
          acc[i][j] += a[i] * b[j];
    }
    __syncthreads();
  }

  #pragma unroll
  for (int i = 0; i < 8; ++i) {
    int r = row0 + ty * 8 + i;
    if (r < M) {
      float4 v0 = make_float4(acc[i][0], acc[i][1], acc[i][2], acc[i][3]);
      float4 v1 = make_float4(acc[i][4], acc[i][5], acc[i][6], acc[i][7]);
      *reinterpret_cast<float4*>(&C[(size_t)r * NC + col0 + tx * 8])     = v0;
      *reinterpret_cast<float4*>(&C[(size_t)r * NC + col0 + tx * 8 + 4]) = v1;
    }
  }
}

// ---------------- per-node s,d dots: s[n,h] = sum_o Wh[n,h,o]*a[h,o] ----------------

template<int O>
__global__ void sd_kernel(const float* __restrict__ Wh, const float* __restrict__ a,
                          float* __restrict__ s, float* __restrict__ d) {
  int n = blockIdx.x;
  int t = threadIdx.x;          // t = h*O + o; blockDim = NH*O
  int h = t / O, o = t % O;
  float v  = Wh[(size_t)n * (NH * O) + t];
  float vs = v * a[h * 2 * O + o];
  float vd = v * a[h * 2 * O + O + o];
  #pragma unroll
  for (int off = O / 2; off > 0; off >>= 1) {
    vs += __shfl_down(vs, off, O);
    vd += __shfl_down(vd, off, O);
  }
  if (o == 0) { s[n * NH + h] = vs; d[n * NH + h] = vd; }
}

// ---------------- layer-1 aggregation: wave per (node, head), 64 lanes = O ----------------
// h1[n, h*64+o] = relu( (sum_e w_e * Wh1[dst_e, h, o]) / (sum_e w_e + eps) )

__global__ __launch_bounds__(256) void agg1_kernel(const float* __restrict__ Wh,
                                                   const float* __restrict__ s1,
                                                   const float* __restrict__ d1,
                                                   const int* __restrict__ row,
                                                   const int* __restrict__ dsts,
                                                   float* __restrict__ h1) {
  int n    = blockIdx.x;
  int h    = threadIdx.x >> 6;
  int lane = threadIdx.x & 63;
  int start = row[n], end = row[n + 1];
  float sn = s1[n * NH + h];
  float acc = 0.f, den = 0.f;
  for (int c = start; c < end; c += 64) {
    int m = min(64, end - c);
    float w = 0.f;
    int dn = 0;
    if (lane < m) {
      dn = dsts[c + lane];
      float e  = sn + d1[dn * NH + h];
      float le = e > 0.f ? e : 0.2f * e;
      w = expf(-le);
    }
    for (int j = 0; j < m; ++j) {
      float wj = __shfl(w, j);
      int   dj = __shfl(dn, j);
      acc += wj * Wh[(size_t)dj * HO1 + h * 64 + lane];
      den += wj;
    }
  }
  float v = acc / (den + 1e-10f);
  h1[(size_t)n * HO1 + h * 64 + lane] = v > 0.f ? v : 0.f;
}

// ---------------- layer-2 aggregation + head-mean + relu -> out(N,32) ----------------
// 128 threads/block: t = h*32+o

__global__ __launch_bounds__(128) void agg2_kernel(const float* __restrict__ Wh,
                                                   const float* __restrict__ s2,
                                                   const float* __restrict__ d2,
                                                   const int* __restrict__ row,
                                                   const int* __restrict__ dsts,
                                                   float* __restrict__ out) {
  __shared__ float red[128];
  int n    = blockIdx.x;
  int t    = threadIdx.x;
  int h    = t >> 5;
  int lane = t & 63;
  int start = row[n], end = row[n + 1];
  float sn = s2[n * NH + h];
  float acc = 0.f, den = 0.f;
  for (int c = start; c < end; c += 32) {
    int m = min(32, end - c);
    int j32 = lane & 31;
    float w = 0.f;
    int dn = 0;
    if (j32 < m) {
      dn = dsts[c + j32];
      float e  = sn + d2[dn * NH + h];
      float le = e > 0.f ? e : 0.2f * e;
      w = expf(-le);
    }
    for (int j = 0; j < m; ++j) {
      float wj = __shfl(w, (lane & 32) + j);
      int   dj = __shfl(dn, (lane & 32) + j);
      acc += wj * Wh[(size_t)dj * HO2 + t];
      den += wj;
    }
  }
  red[t] = acc / (den + 1e-10f);
  __syncthreads();
  if (t < 32) {
    float v = 0.25f * (red[t] + red[t + 32] + red[t + 64] + red[t + 96]);
    out[(size_t)n * 32 + t] = v > 0.f ? v : 0.f;
  }
}

// ---------------- launch ----------------

extern "C" void kernel_launch(void* const* d_in, const int* in_sizes, int n_in,
                              void* d_out, int out_size, void* d_ws, size_t ws_size,
                              hipStream_t stream) {
  const float* features = (const float*)d_in[0];
  const int*   src      = (const int*)d_in[1];
  const int*   dst      = (const int*)d_in[2];
  const float* W1       = (const float*)d_in[3];
  const float* a1       = (const float*)d_in[4];
  const float* W2       = (const float*)d_in[5];
  const float* a2       = (const float*)d_in[6];
  float* out = (float*)d_out;
  const int N = in_sizes[0] / F_IN;
  const int E = in_sizes[1];

  char* wsp = (char*)d_ws;
  size_t off = 0;
  auto alloc = [&](size_t bytes) {
    void* p = wsp + off;
    off = (off + bytes + 255) & ~size_t(255);
    return p;
  };
  int*   cnt    = (int*)alloc((size_t)N * 4);
  int*   cursor = (int*)alloc((size_t)N * 4);
  int*   row    = (int*)alloc((size_t)(N + 1) * 4);
  int*   dsts   = (int*)alloc((size_t)E * 4);
  float* B1r    = (float*)alloc((size_t)F_IN * HO1 * 4);
  float* B2r    = (float*)alloc((size_t)HO1 * HO2 * 4);
  float* s1     = (float*)alloc((size_t)N * NH * 4);
  float* d1     = (float*)alloc((size_t)N * NH * 4);
  float* s2     = (float*)alloc((size_t)N * NH * 4);
  float* d2     = (float*)alloc((size_t)N * NH * 4);
  float* h1     = (float*)alloc((size_t)N * HO1 * 4);
  float* Wh1    = (float*)alloc((size_t)N * HO1 * 4);
  float* Wh2    = Wh1;  // dead after agg1; reuse for layer-2 Wh

  // CSR (shared by both layers)
  zero_i32<<<(N + 255) / 256, 256, 0, stream>>>(cnt, N);
  count_kernel<<<(E + 255) / 256, 256, 0, stream>>>(src, cnt, E);
  scan_kernel<<<1, 1024, 0, stream>>>(cnt, row, cursor, N);
  scatter_kernel<<<(E + 255) / 256, 256, 0, stream>>>(src, dst, cursor, dsts, E);

  // weights -> row-major (K, H*O)
  rearrange_W<F_IN, HID><<<(F_IN * HO1 + 255) / 256, 256, 0, stream>>>(W1, B1r, F_IN * HO1);
  rearrange_W<HO1, OUTD><<<(HO1 * HO2 + 255) / 256, 256, 0, stream>>>(W2, B2r, HO1 * HO2);

  // layer 1
  dim3 g1((N + 127) / 128, HO1 / 128);
  gemm_f32<F_IN, HO1><<<g1, 256, 0, stream>>>(features, B1r, Wh1, N);
  sd_kernel<HID><<<N, NH * HID, 0, stream>>>(Wh1, a1, s1, d1);
  agg1_kernel<<<N, 256, 0, stream>>>(Wh1, s1, d1, row, dsts, h1);

  // layer 2
  dim3 g2((N + 127) / 128, HO2 / 128);
  gemm_f32<HO1, HO2><<<g2, 256, 0, stream>>>(h1, B2r, Wh2, N);
  sd_kernel<OUTD><<<N, NH * OUTD, 0, stream>>>(Wh2, a2, s2, d2);
  agg2_kernel<<<N, 128, 0, stream>>>(Wh2, s2, d2, row, dsts, out);
}

// Round 8
// 683.295 us; speedup vs baseline: 1.4283x; 1.4283x over previous
//
#include <hip/hip_runtime.h>

typedef __attribute__((ext_vector_type(8))) short short8;
typedef __attribute__((ext_vector_type(4))) float f32x4;

constexpr int F_IN = 512;
constexpr int HID  = 64;
constexpr int OUTD = 32;
constexpr int NH   = 4;
constexpr int HO1  = NH * HID;   // 256
constexpr int HO2  = NH * OUTD;  // 128

// ---------------- bf16 split helpers ----------------

__device__ __forceinline__ short bf16h(float x) {
  unsigned u = __float_as_uint(x);
  u = (u + 0x7FFFu + ((u >> 16) & 1u)) >> 16;   // RNE
  return (short)(unsigned short)u;
}
__device__ __forceinline__ float bf16f(short h) {
  return __uint_as_float(((unsigned)(unsigned short)h) << 16);
}

// ---------------- CSR build ----------------

__global__ void zero_i32(int* p, int n) {
  int i = blockIdx.x * blockDim.x + threadIdx.x;
  if (i < n) p[i] = 0;
}

__global__ void count_kernel(const int* __restrict__ src, int* __restrict__ cnt, int E) {
  int i = blockIdx.x * blockDim.x + threadIdx.x;
  if (i < E) atomicAdd(&cnt[src[i]], 1);
}

__global__ void scan_kernel(const int* __restrict__ cnt, int* __restrict__ row,
                            int* __restrict__ cursor, int n) {
  __shared__ int wsum[16];
  __shared__ int carry_s;
  int t = threadIdx.x;
  if (t == 0) carry_s = 0;
  __syncthreads();
  for (int base = 0; base < n; base += 1024) {
    int i = base + t;
    int c = (i < n) ? cnt[i] : 0;
    int v = c;
    #pragma unroll
    for (int off = 1; off < 64; off <<= 1) {
      int u = __shfl_up(v, off);
      if ((t & 63) >= off) v += u;
    }
    if ((t & 63) == 63) wsum[t >> 6] = v;
    __syncthreads();
    if (t < 16) {
      int w = wsum[t];
      #pragma unroll
      for (int off = 1; off < 16; off <<= 1) {
        int u = __shfl_up(w, off);
        if (t >= off) w += u;
      }
      wsum[t] = w;
    }
    __syncthreads();
    int waveoff = (t >> 6) ? wsum[(t >> 6) - 1] : 0;
    int carry = carry_s;
    int incl = v + waveoff + carry;
    if (i < n) { row[i] = incl - c; cursor[i] = incl - c; }
    __syncthreads();
    if (t == 1023) carry_s = incl;
    __syncthreads();
  }
  if (t == 0) row[n] = carry_s;
}

__global__ void scatter_kernel(const int* __restrict__ src, const int* __restrict__ dst,
                               int* __restrict__ cursor, int* __restrict__ dsts, int E) {
  int i = blockIdx.x * blockDim.x + threadIdx.x;
  if (i < E) {
    int s = src[i];
    int p = atomicAdd(&cursor[s], 1);
    dsts[p] = dst[i];
  }
}

// ------------- W (H,K,O) -> B^T hi/lo bf16, B^T is (H*O) x K row-major -------------

template<int K, int O>
__global__ void splitT_W(const float* __restrict__ W, short* __restrict__ BtH,
                         short* __restrict__ BtL, int total) {
  int i = blockIdx.x * blockDim.x + threadIdx.x;
  if (i >= total) return;
  int o = i % O;
  int k = (i / O) % K;
  int h = i / (O * K);
  float x = W[i];
  short hi = bf16h(x);
  short lo = bf16h(x - bf16f(hi));
  int col = h * O + o;
  BtH[(size_t)col * K + k] = hi;
  BtL[(size_t)col * K + k] = lo;
}

// ---------------- split-bf16 MFMA GEMM: C(MxNC) = A(MxK) @ B(KxNC) ----------------
// A f32 row-major (split hi/lo on the fly); B pre-split transposed bf16 (NC x K).
// Block 128x128, 4 waves in 2x2; per wave 4x4 frags of 16x16x32 MFMA.
// LDS fragment-major: lane-consecutive 16B slots -> conflict-free b128 r/w.
// C/D layout (m89-verified): col = lane&15, row = (lane>>4)*4 + reg.

template<int K, int NC>
__global__ __launch_bounds__(256) void gemm_sb(const float* __restrict__ A,
                                               const short* __restrict__ BtH,
                                               const short* __restrict__ BtL,
                                               float* __restrict__ C, int M) {
  // [0..511] A-hi frags, [512..1023] A-lo, [1024..1535] B-hi, [1536..2047] B-lo
  __shared__ short8 lds8[2048];  // 32 KB
  int t    = threadIdx.x;
  int lane = t & 63;
  int w    = t >> 6;
  int wr   = w >> 1, wc = w & 1;
  int row0 = blockIdx.x * 128, col0 = blockIdx.y * 128;
  int l15  = lane & 15;
  int lk   = (lane >> 4) * 8;

  f32x4 acc[4][4] = {};

  for (int ks = 0; ks < K / 32; ++ks) {
    // stage A: this wave stages frag pairs f = w*2, w*2+1 (16 rows x 32 k each)
    #pragma unroll
    for (int q = 0; q < 2; ++q) {
      int f = w * 2 + q;
      int grow = row0 + f * 16 + l15;
      if (grow >= M) grow = M - 1;                 // clamp (store is guarded)
      const float* src = A + (size_t)grow * K + ks * 32 + lk;
      float4 v0 = *reinterpret_cast<const float4*>(src);
      float4 v1 = *reinterpret_cast<const float4*>(src + 4);
      float xs[8] = {v0.x, v0.y, v0.z, v0.w, v1.x, v1.y, v1.z, v1.w};
      short8 hi, lo;
      #pragma unroll
      for (int e = 0; e < 8; ++e) {
        short h8 = bf16h(xs[e]);
        hi[e] = h8;
        lo[e] = bf16h(xs[e] - bf16f(h8));
      }
      lds8[f * 64 + lane]       = hi;
      lds8[512 + f * 64 + lane] = lo;
    }
    // stage B: 16 slots (8 hi + 8 lo), this wave handles idx = w*4 .. w*4+3
    #pragma unroll
    for (int q = 0; q < 4; ++q) {
      int idx = w * 4 + q;
      const short* Bsrc = (idx < 8) ? BtH : BtL;
      int f = idx & 7;
      int bcol = col0 + f * 16 + l15;
      short8 v = *reinterpret_cast<const short8*>(Bsrc + (size_t)bcol * K + ks * 32 + lk);
      lds8[1024 + idx * 64 + lane] = v;
    }
    __syncthreads();
    short8 ah[4], al[4], bh[4], bl[4];
    #pragma unroll
    for (int m = 0; m < 4; ++m) {
      ah[m] = lds8[(wr * 4 + m) * 64 + lane];
      al[m] = lds8[512 + (wr * 4 + m) * 64 + lane];
    }
    #pragma unroll
    for (int n = 0; n < 4; ++n) {
      bh[n] = lds8[1024 + (wc * 4 + n) * 64 + lane];
      bl[n] = lds8[1536 + (wc * 4 + n) * 64 + lane];
    }
    #pragma unroll
    for (int m = 0; m < 4; ++m)
      #pragma unroll
      for (int n = 0; n < 4; ++n) {
        acc[m][n] = __builtin_amdgcn_mfma_f32_16x16x32_bf16(ah[m], bh[n], acc[m][n], 0, 0, 0);
        acc[m][n] = __builtin_amdgcn_mfma_f32_16x16x32_bf16(ah[m], bl[n], acc[m][n], 0, 0, 0);
        acc[m][n] = __builtin_amdgcn_mfma_f32_16x16x32_bf16(al[m], bh[n], acc[m][n], 0, 0, 0);
      }
    __syncthreads();
  }

  #pragma unroll
  for (int m = 0; m < 4; ++m) {
    int rb = row0 + wr * 64 + m * 16 + (lane >> 4) * 4;
    #pragma unroll
    for (int n = 0; n < 4; ++n) {
      int c = col0 + wc * 64 + n * 16 + l15;
      #pragma unroll
      for (int j = 0; j < 4; ++j) {
        int r = rb + j;
        if (r < M) C[(size_t)r * NC + c] = acc[m][n][j];
      }
    }
  }
}

// ---------------- per-node s,d dots ----------------

template<int O>
__global__ void sd_kernel(const float* __restrict__ Wh, const float* __restrict__ a,
                          float* __restrict__ s, float* __restrict__ d) {
  int n = blockIdx.x;
  int t = threadIdx.x;
  int h = t / O, o = t % O;
  float v  = Wh[(size_t)n * (NH * O) + t];
  float vs = v * a[h * 2 * O + o];
  float vd = v * a[h * 2 * O + O + o];
  #pragma unroll
  for (int off = O / 2; off > 0; off >>= 1) {
    vs += __shfl_down(vs, off, O);
    vd += __shfl_down(vd, off, O);
  }
  if (o == 0) { s[n * NH + h] = vs; d[n * NH + h] = vd; }
}

// ---------------- layer-1 aggregation ----------------

__global__ __launch_bounds__(256) void agg1_kernel(const float* __restrict__ Wh,
                                                   const float* __restrict__ s1,
                                                   const float* __restrict__ d1,
                                                   const int* __restrict__ row,
                                                   const int* __restrict__ dsts,
                                                   float* __restrict__ h1) {
  int n    = blockIdx.x;
  int h    = threadIdx.x >> 6;
  int lane = threadIdx.x & 63;
  int start = row[n], end = row[n + 1];
  float sn = s1[n * NH + h];
  float acc = 0.f, den = 0.f;
  for (int c = start; c < end; c += 64) {
    int m = min(64, end - c);
    float w = 0.f;
    int dn = 0;
    if (lane < m) {
      dn = dsts[c + lane];
      float e  = sn + d1[dn * NH + h];
      float le = e > 0.f ? e : 0.2f * e;
      w = expf(-le);
    }
    for (int j = 0; j < m; ++j) {
      float wj = __shfl(w, j);
      int   dj = __shfl(dn, j);
      acc += wj * Wh[(size_t)dj * HO1 + h * 64 + lane];
      den += wj;
    }
  }
  float v = acc / (den + 1e-10f);
  h1[(size_t)n * HO1 + h * 64 + lane] = v > 0.f ? v : 0.f;
}

// ---------------- layer-2 aggregation + head-mean + relu ----------------

__global__ __launch_bounds__(128) void agg2_kernel(const float* __restrict__ Wh,
                                                   const float* __restrict__ s2,
                                                   const float* __restrict__ d2,
                                                   const int* __restrict__ row,
                                                   const int* __restrict__ dsts,
                                                   float* __restrict__ out) {
  __shared__ float red[128];
  int n    = blockIdx.x;
  int t    = threadIdx.x;
  int h    = t >> 5;
  int lane = t & 63;
  int start = row[n], end = row[n + 1];
  float sn = s2[n * NH + h];
  float acc = 0.f, den = 0.f;
  for (int c = start; c < end; c += 32) {
    int m = min(32, end - c);
    int j32 = lane & 31;
    float w = 0.f;
    int dn = 0;
    if (j32 < m) {
      dn = dsts[c + j32];
      float e  = sn + d2[dn * NH + h];
      float le = e > 0.f ? e : 0.2f * e;
      w = expf(-le);
    }
    for (int j = 0; j < m; ++j) {
      float wj = __shfl(w, (lane & 32) + j);
      int   dj = __shfl(dn, (lane & 32) + j);
      acc += wj * Wh[(size_t)dj * HO2 + t];
      den += wj;
    }
  }
  red[t] = acc / (den + 1e-10f);
  __syncthreads();
  if (t < 32) {
    float v = 0.25f * (red[t] + red[t + 32] + red[t + 64] + red[t + 96]);
    out[(size_t)n * 32 + t] = v > 0.f ? v : 0.f;
  }
}

// ---------------- launch ----------------

extern "C" void kernel_launch(void* const* d_in, const int* in_sizes, int n_in,
                              void* d_out, int out_size, void* d_ws, size_t ws_size,
                              hipStream_t stream) {
  const float* features = (const float*)d_in[0];
  const int*   src      = (const int*)d_in[1];
  const int*   dst      = (const int*)d_in[2];
  const float* W1       = (const float*)d_in[3];
  const float* a1       = (const float*)d_in[4];
  const float* W2       = (const float*)d_in[5];
  const float* a2       = (const float*)d_in[6];
  float* out = (float*)d_out;
  const int N = in_sizes[0] / F_IN;
  const int E = in_sizes[1];

  char* wsp = (char*)d_ws;
  size_t off = 0;
  auto alloc = [&](size_t bytes) {
    void* p = wsp + off;
    off = (off + bytes + 255) & ~size_t(255);
    return p;
  };
  int*   cnt    = (int*)alloc((size_t)N * 4);
  int*   cursor = (int*)alloc((size_t)N * 4);
  int*   row    = (int*)alloc((size_t)(N + 1) * 4);
  int*   dsts   = (int*)alloc((size_t)E * 4);
  short* B1tH   = (short*)alloc((size_t)HO1 * F_IN * 2);
  short* B1tL   = (short*)alloc((size_t)HO1 * F_IN * 2);
  short* B2tH   = (short*)alloc((size_t)HO2 * HO1 * 2);
  short* B2tL   = (short*)alloc((size_t)HO2 * HO1 * 2);
  float* s1     = (float*)alloc((size_t)N * NH * 4);
  float* d1     = (float*)alloc((size_t)N * NH * 4);
  float* s2     = (float*)alloc((size_t)N * NH * 4);
  float* d2     = (float*)alloc((size_t)N * NH * 4);
  float* h1     = (float*)alloc((size_t)N * HO1 * 4);
  float* Wh1    = (float*)alloc((size_t)N * HO1 * 4);
  float* Wh2    = Wh1;  // dead after agg1; reuse for layer-2 Wh

  // CSR (shared by both layers)
  zero_i32<<<(N + 255) / 256, 256, 0, stream>>>(cnt, N);
  count_kernel<<<(E + 255) / 256, 256, 0, stream>>>(src, cnt, E);
  scan_kernel<<<1, 1024, 0, stream>>>(cnt, row, cursor, N);
  scatter_kernel<<<(E + 255) / 256, 256, 0, stream>>>(src, dst, cursor, dsts, E);

  // weights -> transposed split-bf16
  splitT_W<F_IN, HID><<<(F_IN * HO1 + 255) / 256, 256, 0, stream>>>(W1, B1tH, B1tL, F_IN * HO1);
  splitT_W<HO1, OUTD><<<(HO1 * HO2 + 255) / 256, 256, 0, stream>>>(W2, B2tH, B2tL, HO1 * HO2);

  // layer 1
  dim3 g1((N + 127) / 128, HO1 / 128);
  gemm_sb<F_IN, HO1><<<g1, 256, 0, stream>>>(features, B1tH, B1tL, Wh1, N);
  sd_kernel<HID><<<N, NH * HID, 0, stream>>>(Wh1, a1, s1, d1);
  agg1_kernel<<<N, 256, 0, stream>>>(Wh1, s1, d1, row, dsts, h1);

  // layer 2
  dim3 g2((N + 127) / 128, HO2 / 128);
  gemm_sb<HO1, HO2><<<g2, 256, 0, stream>>>(h1, B2tH, B2tL, Wh2, N);
  sd_kernel<OUTD><<<N, NH * OUTD, 0, stream>>>(Wh2, a2, s2, d2);
  agg2_kernel<<<N, 128, 0, stream>>>(Wh2, s2, d2, row, dsts, out);
}

// Round 10
// 595.740 us; speedup vs baseline: 1.6382x; 1.1470x over previous
//
#include <hip/hip_runtime.h>

typedef __attribute__((ext_vector_type(8))) short short8;
typedef __attribute__((ext_vector_type(4))) float f32x4;

constexpr int F_IN = 512;
constexpr int HID  = 64;
constexpr int OUTD = 32;
constexpr int NH   = 4;
constexpr int HO1  = NH * HID;   // 256
constexpr int HO2  = NH * OUTD;  // 128

// ---------------- bf16 split helpers ----------------

__device__ __forceinline__ short bf16h(float x) {
  unsigned u = __float_as_uint(x);
  u = (u + 0x7FFFu + ((u >> 16) & 1u)) >> 16;   // RNE
  return (short)(unsigned short)u;
}
__device__ __forceinline__ float bf16f(short h) {
  return __uint_as_float(((unsigned)(unsigned short)h) << 16);
}

// ---------------- CSR build ----------------

__global__ void zero_i32(int* p, int n) {
  int i = blockIdx.x * blockDim.x + threadIdx.x;
  if (i < n) p[i] = 0;
}

__global__ void count_kernel(const int* __restrict__ src, int* __restrict__ cnt, int E) {
  int i = blockIdx.x * blockDim.x + threadIdx.x;
  if (i < E) atomicAdd(&cnt[src[i]], 1);
}

__global__ void scan_kernel(const int* __restrict__ cnt, int* __restrict__ row,
                            int* __restrict__ cursor, int n) {
  __shared__ int wsum[16];
  __shared__ int carry_s;
  int t = threadIdx.x;
  if (t == 0) carry_s = 0;
  __syncthreads();
  for (int base = 0; base < n; base += 1024) {
    int i = base + t;
    int c = (i < n) ? cnt[i] : 0;
    int v = c;
    #pragma unroll
    for (int off = 1; off < 64; off <<= 1) {
      int u = __shfl_up(v, off);
      if ((t & 63) >= off) v += u;
    }
    if ((t & 63) == 63) wsum[t >> 6] = v;
    __syncthreads();
    if (t < 16) {
      int w = wsum[t];
      #pragma unroll
      for (int off = 1; off < 16; off <<= 1) {
        int u = __shfl_up(w, off);
        if (t >= off) w += u;
      }
      wsum[t] = w;
    }
    __syncthreads();
    int waveoff = (t >> 6) ? wsum[(t >> 6) - 1] : 0;
    int carry = carry_s;
    int incl = v + waveoff + carry;
    if (i < n) { row[i] = incl - c; cursor[i] = incl - c; }
    __syncthreads();
    if (t == 1023) carry_s = incl;
    __syncthreads();
  }
  if (t == 0) row[n] = carry_s;
}

__global__ void scatter_kernel(const int* __restrict__ src, const int* __restrict__ dst,
                               int* __restrict__ cursor, int* __restrict__ dsts, int E) {
  int i = blockIdx.x * blockDim.x + threadIdx.x;
  if (i < E) {
    int s = src[i];
    int p = atomicAdd(&cursor[s], 1);
    dsts[p] = dst[i];
  }
}

// ------------- W (H,K,O) -> B^T hi/lo bf16, B^T is (H*O) x K row-major -------------

template<int K, int O>
__global__ void splitT_W(const float* __restrict__ W, short* __restrict__ BtH,
                         short* __restrict__ BtL, int total) {
  int i = blockIdx.x * blockDim.x + threadIdx.x;
  if (i >= total) return;
  int o = i % O;
  int k = (i / O) % K;
  int h = i / (O * K);
  float x = W[i];
  short hi = bf16h(x);
  short lo = bf16h(x - bf16f(hi));
  int col = h * O + o;
  BtH[(size_t)col * K + k] = hi;
  BtL[(size_t)col * K + k] = lo;
}

// ---------------- split-bf16 MFMA GEMM: C(MxNC) = A(MxK) @ B(KxNC) ----------------

template<int K, int NC>
__global__ __launch_bounds__(256) void gemm_sb(const float* __restrict__ A,
                                               const short* __restrict__ BtH,
                                               const short* __restrict__ BtL,
                                               float* __restrict__ C, int M) {
  // [0..511] A-hi frags, [512..1023] A-lo, [1024..1535] B-hi, [1536..2047] B-lo
  __shared__ short8 lds8[2048];  // 32 KB
  int t    = threadIdx.x;
  int lane = t & 63;
  int w    = t >> 6;
  int wr   = w >> 1, wc = w & 1;
  int row0 = blockIdx.x * 128, col0 = blockIdx.y * 128;
  int l15  = lane & 15;
  int lk   = (lane >> 4) * 8;

  f32x4 acc[4][4] = {};

  for (int ks = 0; ks < K / 32; ++ks) {
    #pragma unroll
    for (int q = 0; q < 2; ++q) {
      int f = w * 2 + q;
      int grow = row0 + f * 16 + l15;
      if (grow >= M) grow = M - 1;                 // clamp (store is guarded)
      const float* src = A + (size_t)grow * K + ks * 32 + lk;
      float4 v0 = *reinterpret_cast<const float4*>(src);
      float4 v1 = *reinterpret_cast<const float4*>(src + 4);
      float xs[8] = {v0.x, v0.y, v0.z, v0.w, v1.x, v1.y, v1.z, v1.w};
      short8 hi, lo;
      #pragma unroll
      for (int e = 0; e < 8; ++e) {
        short h8 = bf16h(xs[e]);
        hi[e] = h8;
        lo[e] = bf16h(xs[e] - bf16f(h8));
      }
      lds8[f * 64 + lane]       = hi;
      lds8[512 + f * 64 + lane] = lo;
    }
    #pragma unroll
    for (int q = 0; q < 4; ++q) {
      int idx = w * 4 + q;
      const short* Bsrc = (idx < 8) ? BtH : BtL;
      int f = idx & 7;
      int bcol = col0 + f * 16 + l15;
      short8 v = *reinterpret_cast<const short8*>(Bsrc + (size_t)bcol * K + ks * 32 + lk);
      lds8[1024 + idx * 64 + lane] = v;
    }
    __syncthreads();
    short8 ah[4], al[4], bh[4], bl[4];
    #pragma unroll
    for (int m = 0; m < 4; ++m) {
      ah[m] = lds8[(wr * 4 + m) * 64 + lane];
      al[m] = lds8[512 + (wr * 4 + m) * 64 + lane];
    }
    #pragma unroll
    for (int n = 0; n < 4; ++n) {
      bh[n] = lds8[1024 + (wc * 4 + n) * 64 + lane];
      bl[n] = lds8[1536 + (wc * 4 + n) * 64 + lane];
    }
    #pragma unroll
    for (int m = 0; m < 4; ++m)
      #pragma unroll
      for (int n = 0; n < 4; ++n) {
        acc[m][n] = __builtin_amdgcn_mfma_f32_16x16x32_bf16(ah[m], bh[n], acc[m][n], 0, 0, 0);
        acc[m][n] = __builtin_amdgcn_mfma_f32_16x16x32_bf16(ah[m], bl[n], acc[m][n], 0, 0, 0);
        acc[m][n] = __builtin_amdgcn_mfma_f32_16x16x32_bf16(al[m], bh[n], acc[m][n], 0, 0, 0);
      }
    __syncthreads();
  }

  #pragma unroll
  for (int m = 0; m < 4; ++m) {
    int rb = row0 + wr * 64 + m * 16 + (lane >> 4) * 4;
    #pragma unroll
    for (int n = 0; n < 4; ++n) {
      int c = col0 + wc * 64 + n * 16 + l15;
      #pragma unroll
      for (int j = 0; j < 4; ++j) {
        int r = rb + j;
        if (r < M) C[(size_t)r * NC + c] = acc[m][n][j];
      }
    }
  }
}

// ---------------- per-node s,d dots ----------------

template<int O>
__global__ void sd_kernel(const float* __restrict__ Wh, const float* __restrict__ a,
                          float* __restrict__ s, float* __restrict__ d) {
  int n = blockIdx.x;
  int t = threadIdx.x;
  int h = t / O, o = t % O;
  float v  = Wh[(size_t)n * (NH * O) + t];
  float vs = v * a[h * 2 * O + o];
  float vd = v * a[h * 2 * O + O + o];
  #pragma unroll
  for (int off = O / 2; off > 0; off >>= 1) {
    vs += __shfl_down(vs, off, O);
    vd += __shfl_down(vd, off, O);
  }
  if (o == 0) { s[n * NH + h] = vs; d[n * NH + h] = vd; }
}

// ---------------- layer-1 aggregation: wave per (node, head) ----------------
// Edge loop 8x unrolled: batch-issue 8 independent gathers, then FMA in the
// ORIGINAL sequential order (numerics identical; kills serialized latency).

__global__ __launch_bounds__(256) void agg1_kernel(const float* __restrict__ Wh,
                                                   const float* __restrict__ s1,
                                                   const float* __restrict__ d1,
                                                   const int* __restrict__ row,
                                                   const int* __restrict__ dsts,
                                                   float* __restrict__ h1) {
  int n    = blockIdx.x;
  int h    = threadIdx.x >> 6;
  int lane = threadIdx.x & 63;
  int start = row[n], end = row[n + 1];
  float sn = s1[n * NH + h];
  float acc = 0.f, den = 0.f;
  const float* __restrict__ Whh = Wh + h * 64 + lane;
  for (int c = start; c < end; c += 64) {
    int m = min(64, end - c);
    float w = 0.f;
    int dn = 0;
    if (lane < m) {
      dn = dsts[c + lane];
      float e  = sn + d1[dn * NH + h];
      float le = e > 0.f ? e : 0.2f * e;
      w = expf(-le);
    }
    int j = 0;
    for (; j + 7 < m; j += 8) {
      float wj[8]; int dj[8];
      #pragma unroll
      for (int u = 0; u < 8; ++u) {
        wj[u] = __shfl(w, j + u);
        dj[u] = __shfl(dn, j + u);
      }
      float x[8];
      #pragma unroll
      for (int u = 0; u < 8; ++u) x[u] = Whh[(size_t)dj[u] * HO1];
      #pragma unroll
      for (int u = 0; u < 8; ++u) { acc += wj[u] * x[u]; den += wj[u]; }
    }
    for (; j < m; ++j) {
      float wj = __shfl(w, j);
      int   dj = __shfl(dn, j);
      acc += wj * Whh[(size_t)dj * HO1];
      den += wj;
    }
  }
  float v = acc / (den + 1e-10f);
  h1[(size_t)n * HO1 + h * 64 + lane] = v > 0.f ? v : 0.f;
}

// ---------------- layer-2 aggregation + head-mean + relu ----------------

__global__ __launch_bounds__(128) void agg2_kernel(const float* __restrict__ Wh,
                                                   const float* __restrict__ s2,
                                                   const float* __restrict__ d2,
                                                   const int* __restrict__ row,
                                                   const int* __restrict__ dsts,
                                                   float* __restrict__ out) {
  __shared__ float red[128];
  int n    = blockIdx.x;
  int t    = threadIdx.x;
  int h    = t >> 5;
  int lane = t & 63;
  int start = row[n], end = row[n + 1];
  float sn = s2[n * NH + h];
  float acc = 0.f, den = 0.f;
  const float* __restrict__ Wht = Wh + t;
  for (int c = start; c < end; c += 32) {
    int m = min(32, end - c);
    int j32 = lane & 31;
    float w = 0.f;
    int dn = 0;
    if (j32 < m) {
      dn = dsts[c + j32];
      float e  = sn + d2[dn * NH + h];
      float le = e > 0.f ? e : 0.2f * e;
      w = expf(-le);
    }
    int base = lane & 32;
    int j = 0;
    for (; j + 7 < m; j += 8) {
      float wj[8]; int dj[8];
      #pragma unroll
      for (int u = 0; u < 8; ++u) {
        wj[u] = __shfl(w, base + j + u);
        dj[u] = __shfl(dn, base + j + u);
      }
      float x[8];
      #pragma unroll
      for (int u = 0; u < 8; ++u) x[u] = Wht[(size_t)dj[u] * HO2];
      #pragma unroll
      for (int u = 0; u < 8; ++u) { acc += wj[u] * x[u]; den += wj[u]; }
    }
    for (; j < m; ++j) {
      float wj = __shfl(w, base + j);
      int   dj = __shfl(dn, base + j);
      acc += wj * Wht[(size_t)dj * HO2];
      den += wj;
    }
  }
  red[t] = acc / (den + 1e-10f);
  __syncthreads();
  if (t < 32) {
    float v = 0.25f * (red[t] + red[t + 32] + red[t + 64] + red[t + 96]);
    out[(size_t)n * 32 + t] = v > 0.f ? v : 0.f;
  }
}

// ---------------- launch ----------------

extern "C" void kernel_launch(void* const* d_in, const int* in_sizes, int n_in,
                              void* d_out, int out_size, void* d_ws, size_t ws_size,
                              hipStream_t stream) {
  const float* features = (const float*)d_in[0];
  const int*   src      = (const int*)d_in[1];
  const int*   dst      = (const int*)d_in[2];
  const float* W1       = (const float*)d_in[3];
  const float* a1       = (const float*)d_in[4];
  const float* W2       = (const float*)d_in[5];
  const float* a2       = (const float*)d_in[6];
  float* out = (float*)d_out;
  const int N = in_sizes[0] / F_IN;
  const int E = in_sizes[1];

  char* wsp = (char*)d_ws;
  size_t off = 0;
  auto alloc = [&](size_t bytes) {
    void* p = wsp + off;
    off = (off + bytes + 255) & ~size_t(255);
    return p;
  };
  int*   cnt    = (int*)alloc((size_t)N * 4);
  int*   cursor = (int*)alloc((size_t)N * 4);
  int*   row    = (int*)alloc((size_t)(N + 1) * 4);
  int*   dsts   = (int*)alloc((size_t)E * 4);
  short* B1tH   = (short*)alloc((size_t)HO1 * F_IN * 2);
  short* B1tL   = (short*)alloc((size_t)HO1 * F_IN * 2);
  short* B2tH   = (short*)alloc((size_t)HO2 * HO1 * 2);
  short* B2tL   = (short*)alloc((size_t)HO2 * HO1 * 2);
  float* s1     = (float*)alloc((size_t)N * NH * 4);
  float* d1     = (float*)alloc((size_t)N * NH * 4);
  float* s2     = (float*)alloc((size_t)N * NH * 4);
  float* d2     = (float*)alloc((size_t)N * NH * 4);
  float* h1     = (float*)alloc((size_t)N * HO1 * 4);
  float* Wh1    = (float*)alloc((size_t)N * HO1 * 4);
  float* Wh2    = Wh1;  // dead after agg1; reuse for layer-2 Wh

  // CSR (shared by both layers)
  zero_i32<<<(N + 255) / 256, 256, 0, stream>>>(cnt, N);
  count_kernel<<<(E + 255) / 256, 256, 0, stream>>>(src, cnt, E);
  scan_kernel<<<1, 1024, 0, stream>>>(cnt, row, cursor, N);
  scatter_kernel<<<(E + 255) / 256, 256, 0, stream>>>(src, dst, cursor, dsts, E);

  // weights -> transposed split-bf16
  splitT_W<F_IN, HID><<<(F_IN * HO1 + 255) / 256, 256, 0, stream>>>(W1, B1tH, B1tL, F_IN * HO1);
  splitT_W<HO1, OUTD><<<(HO1 * HO2 + 255) / 256, 256, 0, stream>>>(W2, B2tH, B2tL, HO1 * HO2);

  // layer 1
  dim3 g1((N + 127) / 128, HO1 / 128);
  gemm_sb<F_IN, HO1><<<g1, 256, 0, stream>>>(features, B1tH, B1tL, Wh1, N);
  sd_kernel<HID><<<N, NH * HID, 0, stream>>>(Wh1, a1, s1, d1);
  agg1_kernel<<<N, 256, 0, stream>>>(Wh1, s1, d1, row, dsts, h1);

  // layer 2
  dim3 g2((N + 127) / 128, HO2 / 128);
  gemm_sb<HO1, HO2><<<g2, 256, 0, stream>>>(h1, B2tH, B2tL, Wh2, N);
  sd_kernel<OUTD><<<N, NH * OUTD, 0, stream>>>(Wh2, a2, s2, d2);
  agg2_kernel<<<N, 128, 0, stream>>>(Wh2, s2, d2, row, dsts, out);
}